// Round 13
// baseline (264.747 us; speedup 1.0000x reference)
//
#include <hip/hip_runtime.h>
#include <stdint.h>

#define NROW    8192
#define CDIM    256
#define NCODE   16384
#define MARGINF 6.0e-5f

typedef short short8 __attribute__((ext_vector_type(8)));
typedef float floatx4 __attribute__((ext_vector_type(4)));

__device__ inline ushort f2bf(float f) {
    unsigned u = __builtin_bit_cast(unsigned, f);
    unsigned r = (u + 0x7fffu + ((u >> 16) & 1u)) >> 16;
    return (ushort)r;
}
__device__ inline unsigned fsort(float v) {
    unsigned u = __builtin_bit_cast(unsigned, v);
    return (u >> 31) ? ~u : (u | 0x80000000u);
}

__device__ inline void gl_lds16(const ushort* g, ushort* lds) {
    __builtin_amdgcn_global_load_lds(
        (const __attribute__((address_space(1))) unsigned int*)(g),
        (__attribute__((address_space(3))) unsigned int*)(lds),
        16, 0, 0);
}

// ---------------------------------------------------------------------------
// Fused prep: blocks 0..2047 = x transpose/convert (32x32 LDS tiles);
// blocks 2048..3071 = w bf16 (float4 loads) + exact np-pairwise S2
// (16 threads/row; butterfly reproduces ((r0+r1)+(r2+r3))+((r4+r5)+(r6+r7)),
// then hs0+hs1). Block 2048 zeroes the rescore completion counter.
// ---------------------------------------------------------------------------
__global__ __launch_bounds__(256) void prep_all(const float* __restrict__ x,
                                                const float* __restrict__ w,
                                                float* __restrict__ xf32,
                                                ushort* __restrict__ xbf,
                                                ushort* __restrict__ wbf,
                                                float* __restrict__ S2a,
                                                int* __restrict__ ctr) {
#pragma clang fp contract(off)
    const int bid = blockIdx.x;
    const int t = threadIdx.x;
    if (bid < 2048) {
        __shared__ float tile[32][33];
        const int b = bid & 7, ht = (bid >> 3) & 31, ct = bid >> 8;
        const int hw0 = ht * 32, c0 = ct * 32;
        {
            const int cc = t >> 5, hh = t & 31;
            #pragma unroll
            for (int i = 0; i < 4; ++i) {
                int cl = cc + i * 8;
                tile[cl][hh] = x[((size_t)(b * 256 + c0 + cl) << 10) + hw0 + hh];
            }
        }
        __syncthreads();
        {
            const int col = t & 31, row = t >> 5;
            #pragma unroll
            for (int i = 0; i < 4; ++i) {
                int r = row + i * 8;
                float v = tile[col][r];
                size_t o = ((size_t)(b * 1024 + hw0 + r) << 8) + c0 + col;
                xf32[o] = v;
                xbf[o] = f2bf(v);
            }
        }
    } else {
        if (bid == 2048 && t == 0) *ctr = 0;
        const int gt = (bid - 2048) * 256 + t;
        const int j = gt >> 4, l16 = gt & 15;
        const int h = l16 >> 3, ai = l16 & 7;
        const float* a = w + ((size_t)j << 8);
        // np 8-accumulator sequential partial (elements ai, ai+8, ..., ai+120)
        float v = a[h * 128 + ai];
        float racc = v * v;
        for (int i = 8; i < 128; i += 8) {
            v = a[h * 128 + ai + i];
            racc = racc + v * v;
        }
        racc = racc + __shfl_xor(racc, 1);
        racc = racc + __shfl_xor(racc, 2);
        racc = racc + __shfl_xor(racc, 4);   // lane ai==0: np bracket per half
        racc = racc + __shfl_xor(racc, 8);   // lane l16==0: hs0 + hs1 (np order)
        if (l16 == 0) S2a[j] = racc;
        // bf16 conversion: contiguous 16-elem segment per thread, float4 loads
        const float4* seg4 = (const float4*)(a + l16 * 16);
        ushort* oseg = wbf + ((size_t)j << 8) + l16 * 16;
        #pragma unroll
        for (int i = 0; i < 4; ++i) {
            float4 vv = seg4[i];
            *(ushort4*)(oseg + i * 4) =
                make_ushort4(f2bf(vv.x), f2bf(vv.y), f2bf(vv.z), f2bf(vv.w));
        }
    }
}

// ---------------------------------------------------------------------------
// bf16 MFMA GEMM, codes on M / queries on N. Per (query, 64-code group) one
// packed u32: [min fp16 | (second-min)-min delta fp16-top8 trunc-DOWN | idx6].
// In-lane merge over the 4 mi tiles, then one 2-level quad merge per ni with
// first-index tie-break. bm32[n][256], group id = blockIdx.y*2 + wr.
// (unchanged from R12: 95 us, MfmaUtil 31%, 0 conflicts)
// ---------------------------------------------------------------------------
__global__ __launch_bounds__(256) void gemm_min(const ushort* __restrict__ Wb,
                                                const ushort* __restrict__ Xb,
                                                const float* __restrict__ S2a,
                                                unsigned* __restrict__ bm32) {
    __shared__ __attribute__((aligned(16))) ushort As[8192];  // codes  [128][64] swz
    __shared__ __attribute__((aligned(16))) ushort Bs[8192];  // queries[128][64] swz
    __shared__ __attribute__((aligned(16))) unsigned stg32[128][2];

    const int n0 = blockIdx.x * 128;   // query block
    const int j0 = blockIdx.y * 128;   // code block
    const int t  = threadIdx.x;
    const int wv = t >> 6, l = t & 63;
    const int wr = wv >> 1, wc = wv & 1;
    const int q  = l >> 4, c = l & 15;

    const int lr = l >> 3;
    const int lperm = (l & 7) ^ lr;
    const size_t gA0 = ((size_t)(j0 + wv * 32 + lr) << 8) + lperm * 8;
    const size_t gB0 = ((size_t)(n0 + wv * 32 + lr) << 8) + lperm * 8;
    const int ldsbase = wv * 2048;

    floatx4 acc[4][4];
    #pragma unroll
    for (int mi = 0; mi < 4; ++mi)
        #pragma unroll
        for (int ni = 0; ni < 4; ++ni)
            acc[mi][ni] = (floatx4){0.f, 0.f, 0.f, 0.f};

    for (int kb = 0; kb < 4; ++kb) {
        if (kb) __syncthreads();
        #pragma unroll
        for (int ca = 0; ca < 4; ++ca) {
            gl_lds16(Wb + gA0 + ca * 2048 + kb * 64, As + ldsbase + ca * 512);
            gl_lds16(Xb + gB0 + ca * 2048 + kb * 64, Bs + ldsbase + ca * 512);
        }
        __syncthreads();
        #pragma unroll
        for (int kk = 0; kk < 2; ++kk) {
            short8 af[4], bf[4];
            #pragma unroll
            for (int mi = 0; mi < 4; ++mi) {
                int row = wr * 64 + mi * 16 + c;
                int pos = (kk * 4 + q) ^ (c & 7);
                af[mi] = *(const short8*)&As[row * 64 + pos * 8];
            }
            #pragma unroll
            for (int ni = 0; ni < 4; ++ni) {
                int row = wc * 64 + ni * 16 + c;
                int pos = (kk * 4 + q) ^ (c & 7);
                bf[ni] = *(const short8*)&Bs[row * 64 + pos * 8];
            }
            #pragma unroll
            for (int mi = 0; mi < 4; ++mi)
                #pragma unroll
                for (int ni = 0; ni < 4; ++ni)
                    acc[mi][ni] = __builtin_amdgcn_mfma_f32_16x16x32_bf16(
                        af[mi], bf[ni], acc[mi][ni], 0, 0, 0);
        }
    }

    float4 s2v[4];
    #pragma unroll
    for (int mi = 0; mi < 4; ++mi)
        s2v[mi] = *(const float4*)&S2a[j0 + wr * 64 + mi * 16 + (q << 2)];

    #pragma unroll
    for (int ni = 0; ni < 4; ++ni) {
        float M1 = 0.f, M2 = 0.f; int I1 = 0;
        #pragma unroll
        for (int mi = 0; mi < 4; ++mi) {
            float v0 = fmaf(-2.f, acc[mi][ni][0], s2v[mi].x);
            float v1 = fmaf(-2.f, acc[mi][ni][1], s2v[mi].y);
            float v2 = fmaf(-2.f, acc[mi][ni][2], s2v[mi].z);
            float v3 = fmaf(-2.f, acc[mi][ni][3], s2v[mi].w);
            float lo01 = fminf(v0, v1), hi01 = fmaxf(v0, v1);
            float lo23 = fminf(v2, v3), hi23 = fmaxf(v2, v3);
            int i01 = v1 < v0 ? 1 : 0;
            int i23 = v3 < v2 ? 3 : 2;
            float m1 = fminf(lo01, lo23);
            float m2 = fminf(fmaxf(lo01, lo23), lo23 < lo01 ? hi23 : hi01);
            int idx = mi * 16 + (q << 2) + (lo23 < lo01 ? i23 : i01);
            if (mi == 0) { M1 = m1; M2 = m2; I1 = idx; }
            else {
                float nM2 = (m1 < M1) ? fminf(M1, m2) : fminf(M2, m1);
                I1 = (m1 < M1) ? idx : I1;
                M1 = fminf(M1, m1);
                M2 = nM2;
            }
        }
        #pragma unroll
        for (int off = 16; off <= 32; off <<= 1) {
            float oM1 = __shfl_xor(M1, off);
            float oM2 = __shfl_xor(M2, off);
            int   oI1 = __shfl_xor(I1, off);
            float nM2 = fminf(fminf(M2, oM2), fmaxf(M1, oM1));
            bool take = (oM1 < M1) || (oM1 == M1 && oI1 < I1);
            I1 = take ? oI1 : I1;
            M1 = fminf(M1, oM1);
            M2 = nM2;
        }
        if (q == 0) {
            ushort min16 = __builtin_bit_cast(ushort, (_Float16)M1);
            float delta = M2 - M1;
            ushort d16 = __builtin_bit_cast(ushort, (_Float16)delta);
            ushort d8 = d16 >> 8;
            float rec = (float)__builtin_bit_cast(_Float16, (ushort)(d8 << 8));
            if (rec > delta && d8) d8--;   // stored delta must be <= actual
            stg32[wc * 64 + ni * 16 + c][wr] =
                ((unsigned)min16 << 16) | ((unsigned)d8 << 8) | (unsigned)I1;
        }
    }
    __syncthreads();
    if (t < 128) {
        uint2 v = *(const uint2*)&stg32[t][0];
        *(uint2*)(bm32 + ((size_t)(n0 + t) << 8) + blockIdx.y * 2) = v;
    }
}

// ---------------------------------------------------------------------------
// 16 ROWS PER BLOCK (4 per wave, serial). Per row: prune 256 packed groups,
// exact np-fp32 rescore (candidate/lane, register-batched loads), first-index
// tie-break. Winners' w rows staged to padded LDS tile; thread t = channel c
// writes a full 64B line (16 hw) of xq_img. Loss fused: per-block partial +
// ctr/last-block deterministic reduction (ctr zeroed in prep_all).
// ---------------------------------------------------------------------------
__global__ __launch_bounds__(256) void rescore9(const unsigned* __restrict__ bm32,
                                                const float* __restrict__ xf32,
                                                const float* __restrict__ w,
                                                const float* __restrict__ S2a,
                                                float* __restrict__ out,
                                                float* __restrict__ xcode,
                                                float* __restrict__ lpart,
                                                int* __restrict__ ctr,
                                                float* __restrict__ loss) {
#pragma clang fp contract(off)
    __shared__ float xs[16][256];       // 16 KB, row stride 1 KB (16B aligned)
    __shared__ float wt[16][260];       // padded: 2-way-free transpose reads
    __shared__ short sing[4][128];
    __shared__ short blk[4][16];
    __shared__ int ns[4], nb[4];
    __shared__ float lred[4];
    __shared__ int lastf;
    __shared__ float red[256];

    const int t = threadIdx.x, wv = t >> 6, l = t & 63;
    const int n0 = blockIdx.x * 16;

    // stage all 16 x rows (flat coalesced float4)
    #pragma unroll
    for (int i = 0; i < 4; ++i) {
        float4 v = *(const float4*)&xf32[((size_t)n0 << 8) + i * 1024 + t * 4];
        *(float4*)&xs[0][i * 1024 + t * 4] = v;
    }
    __syncthreads();

    float wavloss = 0.f;
    for (int rr = 0; rr < 4; ++rr) {
        const int row = wv * 4 + rr;
        const int n = n0 + row;
        if (l == 0) { ns[wv] = 0; nb[wv] = 0; }

        const uint4 e = *(const uint4*)(bm32 + ((size_t)n << 8) + l * 4);
        unsigned ee[4] = {e.x, e.y, e.z, e.w};
        float vals[4];
        #pragma unroll
        for (int i = 0; i < 4; ++i)
            vals[i] = (float)__builtin_bit_cast(_Float16, (ushort)(ee[i] >> 16));
        float vmin = fminf(fminf(vals[0], vals[1]), fminf(vals[2], vals[3]));
        #pragma unroll
        for (int off = 1; off <= 32; off <<= 1)
            vmin = fminf(vmin, __shfl_xor(vmin, off));
        const float thr = vmin + MARGINF;
        #pragma unroll
        for (int i = 0; i < 4; ++i) {
            if (vals[i] <= thr) {
                const int jb = l * 4 + i;
                int p = atomicAdd(&ns[wv], 1);
                if (p < 128) sing[wv][p] = (short)(jb * 64 + (int)(ee[i] & 63u));
                float dr = (float)__builtin_bit_cast(_Float16,
                               (ushort)(((ee[i] >> 8) & 0xFFu) << 8));
                if (vals[i] + dr <= thr) {
                    int pb = atomicAdd(&nb[wv], 1);
                    if (pb < 16) blk[wv][pb] = (short)jb;
                }
            }
        }

        // exact np pairwise S1 (lanes 0..15: half l>>3, accumulator l&7)
        float racc = 0.f;
        if (l < 16) {
            const float* a_ = &xs[row][(l >> 3) * 128];
            const int ai = l & 7;
            float v = a_[ai];
            racc = v * v;
            for (int i = 8; i < 128; i += 8) { v = a_[i + ai]; racc = racc + v * v; }
        }
        racc = racc + __shfl_xor(racc, 1);
        racc = racc + __shfl_xor(racc, 2);
        racc = racc + __shfl_xor(racc, 4);
        racc = racc + __shfl_xor(racc, 8);   // lane 0: hs0 + hs1 (np order)
        const float S1n = __shfl(racc, 0);

        const int nsv = ns[wv] < 128 ? ns[wv] : 128;
        const int nbv = nb[wv] < 16 ? nb[wv] : 16;
        const int ntot = nsv + nbv * 64;
        unsigned long long best = ~0ull;
        for (int s = l; s < ntot; s += 64) {
            const int j = (s < nsv)
                ? (int)sing[wv][s]
                : (int)blk[wv][(s - nsv) >> 6] * 64 + ((s - nsv) & 63);
            const float4* wr4 = (const float4*)(w + ((size_t)j << 8));
            float g = 0.f;
            #pragma unroll
            for (int half = 0; half < 4; ++half) {
                float4 buf[16];
                #pragma unroll
                for (int i = 0; i < 16; ++i) buf[i] = wr4[half * 16 + i];
                #pragma unroll
                for (int i = 0; i < 16; ++i) {   // sequential FMA, k-order (BLAS)
                    const float4 xv4 = *(const float4*)&xs[row][half * 64 + i * 4];
                    g = fmaf(xv4.x, buf[i].x, g);
                    g = fmaf(xv4.y, buf[i].y, g);
                    g = fmaf(xv4.z, buf[i].z, g);
                    g = fmaf(xv4.w, buf[i].w, g);
                }
            }
            float d = (S1n + S2a[j]) - 2.0f * g;
            unsigned long long key = ((unsigned long long)fsort(d) << 32) | (unsigned)j;
            if (key < best) best = key;
        }
        #pragma unroll
        for (int off = 1; off <= 32; off <<= 1) {
            unsigned long long o = __shfl_xor(best, off);
            if (o < best) best = o;
        }
        const int J = (int)(best & 0xffffffffu);
        if (l == 0) xcode[n] = (float)J;

        // stage w[J] into transpose tile + loss partial (row is L1-hot)
        const float4 wj = *(const float4*)&w[((size_t)J << 8) + l * 4];
        *(float4*)&wt[row][l * 4] = wj;
        const float4 xv4 = *(const float4*)&xs[row][l * 4];
        float d0 = wj.x - xv4.x, d1 = wj.y - xv4.y;
        float d2 = wj.z - xv4.z, d3 = wj.w - xv4.w;
        wavloss += (d0 * d0 + d1 * d1) + (d2 * d2 + d3 * d3);
    }
    #pragma unroll
    for (int off = 1; off <= 32; off <<= 1) wavloss += __shfl_xor(wavloss, off);
    if (l == 0) lred[wv] = wavloss;
    __syncthreads();

    // output: thread t = channel c; full 64B line (16 hw values)
    {
        const int b = n0 >> 10, hw0 = n0 & 1023;
        float* ob = out + (((size_t)((b << 8) + t)) << 10) + hw0;
        float v[16];
        #pragma unroll
        for (int r = 0; r < 16; ++r) v[r] = wt[r][t];
        *(float4*)(ob)      = make_float4(v[0],  v[1],  v[2],  v[3]);
        *(float4*)(ob + 4)  = make_float4(v[4],  v[5],  v[6],  v[7]);
        *(float4*)(ob + 8)  = make_float4(v[8],  v[9],  v[10], v[11]);
        *(float4*)(ob + 12) = make_float4(v[12], v[13], v[14], v[15]);
    }

    if (t == 0) {
        lpart[blockIdx.x] = (lred[0] + lred[1]) + (lred[2] + lred[3]);
        __threadfence();
        int old = atomicAdd(ctr, 1);
        lastf = (old == 511) ? 1 : 0;
    }
    __syncthreads();
    if (lastf) {
        __threadfence();
        float s = lpart[t] + lpart[t + 256];
        red[t] = s;
        __syncthreads();
        for (int k = 128; k > 0; k >>= 1) {
            if (t < k) red[t] += red[t + k];
            __syncthreads();
        }
        if (t == 0) *loss = red[0] * (1.25f / 2097152.0f);
    }
}

// ---------------------------------------------------------------------------
extern "C" void kernel_launch(void* const* d_in, const int* in_sizes, int n_in,
                              void* d_out, int out_size, void* d_ws, size_t ws_size,
                              hipStream_t stream) {
    const float* x = (const float*)d_in[0];
    const float* w = (const float*)d_in[1];
    float* out = (float*)d_out;

    char* ws = (char*)d_ws;
    const size_t MB = 1024u * 1024u;
    ushort*   xbf   = (ushort*)  (ws);                   //  4 MiB
    float*    xf32  = (float*)   (ws + 4 * MB);          //  8 MiB
    ushort*   wbf   = (ushort*)  (ws + 12 * MB);         //  8 MiB
    float*    S2a   = (float*)   (ws + 20 * MB);         // 64 KiB
    unsigned* bm32  = (unsigned*)(ws + 21 * MB);         //  8 MiB
    float*    lpart = (float*)   (ws + 29 * MB);         //  2 KiB
    int*      ctr   = (int*)     (ws + 29 * MB + 8192);  //  4 B

    float* loss_ptr  = out + 2097152;
    float* xcode_ptr = out + 2097153;

    prep_all<<<dim3(3072),     256, 0, stream>>>(x, w, xf32, xbf, wbf, S2a, ctr);
    gemm_min<<<dim3(64, 128),  256, 0, stream>>>(wbf, xbf, S2a, bm32);
    rescore9<<<dim3(512),      256, 0, stream>>>(bm32, xf32, w, S2a, out,
                                                 xcode_ptr, lpart, ctr, loss_ptr);
}